// Round 5
// baseline (334.189 us; speedup 1.0000x reference)
//
#include <hip/hip_runtime.h>
#include <hip/hip_bf16.h>

// ---------------------------------------------------------------------------
// Multihead attention (single 512-wide head), b=4, n=4096, d=inner=512, fp32 io.
//   qk = x@[Wq*s | Wk]^T   (merged projection, fp32 A converted in-kernel)
//   vw = y@(Wo@Wv)^T       (out-proj folded into V), stored transposed as vwT
//   P  = exp(q@k^T)        (no max subtraction: |S| small, fp32-safe)
//   out = (P@vw)/rowsum(P) + bo   (split-K=2 8-phase PV + deterministic reduce)
// S-GEMM and PV: 256x256 8-phase deep-pipelined kernels (T1+T2+T3+T4+T5).
// ---------------------------------------------------------------------------

typedef unsigned short u16;
typedef __bf16 bf16x8 __attribute__((ext_vector_type(8)));
typedef float f32x4 __attribute__((ext_vector_type(4)));

#define SCALE_QK 0.044194173824159216f /* 1/sqrt(512) */

__device__ __forceinline__ u16 f2bf(float f) {
    __hip_bfloat16 h = __float2bfloat16(f);
    return __builtin_bit_cast(u16, h);
}

__device__ __forceinline__ void load_lds16(const void* g, void* l) {
    __builtin_amdgcn_global_load_lds(
        (const __attribute__((address_space(1))) void*)g,
        (__attribute__((address_space(3))) void*)l, 16, 0, 0);
}

// --------------------------- fp32 -> bf16 convert (weights only) ------------
__global__ void cvt_bf16_kernel(const float* __restrict__ src, u16* __restrict__ dst,
                                int n8, float scale) {
    int i = blockIdx.x * blockDim.x + threadIdx.x;
    if (i >= n8) return;
    const float4* s4 = (const float4*)src;
    float4 v0 = s4[2 * i], v1 = s4[2 * i + 1];
    union { u16 u[8]; uint4 v; } o;
    o.u[0] = f2bf(v0.x * scale); o.u[1] = f2bf(v0.y * scale);
    o.u[2] = f2bf(v0.z * scale); o.u[3] = f2bf(v0.w * scale);
    o.u[4] = f2bf(v1.x * scale); o.u[5] = f2bf(v1.y * scale);
    o.u[6] = f2bf(v1.z * scale); o.u[7] = f2bf(v1.w * scale);
    ((uint4*)dst)[i] = o.v;
}

// --------------------------- Wvo = Wo @ Wv (fp32), 4 rows/block -------------
__global__ void wvo_kernel(const float* __restrict__ Wo, const float* __restrict__ Wv,
                           float* __restrict__ Wvo) {
    int ob = blockIdx.x * 4, t = threadIdx.x;
    float a[4][2] = {{0.f, 0.f}, {0.f, 0.f}, {0.f, 0.f}, {0.f, 0.f}};
    for (int i = 0; i < 512; ++i) {
        float v0 = Wv[i * 512 + t], v1 = Wv[i * 512 + t + 256];
#pragma unroll
        for (int r = 0; r < 4; ++r) {
            float w = Wo[(ob + r) * 512 + i];
            a[r][0] += w * v0;
            a[r][1] += w * v1;
        }
    }
#pragma unroll
    for (int r = 0; r < 4; ++r) {
        Wvo[(ob + r) * 512 + t] = a[r][0];
        Wvo[(ob + r) * 512 + t + 256] = a[r][1];
    }
}

// ===========================================================================
// 256x256 8-phase S-GEMM:  P = exp(A@B^T) -> bf16.  (unchanged from R4)
// ===========================================================================
__launch_bounds__(512, 2)
__global__ void gemm256_exp_kernel(const u16* __restrict__ A, const u16* __restrict__ B,
                                   u16* __restrict__ Cout, int N, int lda, int ldb,
                                   long long sAz, long long sBz, long long sCz) {
    __shared__ u16 lds[8][8192];

    const int tid = threadIdx.x;
    const int wave = tid >> 6, lane = tid & 63;
    const int lr = lane & 15, lg = lane >> 4;
    const int wm = wave >> 2, wn = wave & 3;

    int bid = (blockIdx.z * gridDim.y + blockIdx.y) * gridDim.x + blockIdx.x;
    int lgc = (bid & 7) * 128 + (bid >> 3);
    const int bx = lgc & 15;
    int rem = lgc >> 4;
    const int by = rem & 15, z = rem >> 4;
    const int row0 = by * 256, col0 = bx * 256;

    const u16* Ab = A + (size_t)z * sAz;
    const u16* Bb = B + (size_t)z * sBz;

    const int rb = lane >> 2;
    const int kg8 = ((lane & 3) ^ (rb & 3)) << 3;

    f32x4 acc[8][4];
#pragma unroll
    for (int i = 0; i < 8; ++i)
#pragma unroll
        for (int j = 0; j < 4; ++j) acc[i][j] = (f32x4){0.f, 0.f, 0.f, 0.f};

#define STAGE_HALF(s_, slot_)                                                     \
    {                                                                             \
        const int h_ = (s_)&3, ts_ = (s_) >> 2;                                   \
        const u16* G_ = (h_ & 1) ? Bb : Ab;                                       \
        const int pan_ = (h_ & 1) ? col0 : row0;                                  \
        const int ld_ = (h_ & 1) ? ldb : lda;                                     \
        const int kofs_ = ts_ * 64 + (h_ >> 1) * 32 + kg8;                        \
        _Pragma("unroll") for (int j_ = 0; j_ < 2; ++j_) {                        \
            int r_ = (j_ * 8 + wave) * 16 + rb;                                   \
            load_lds16(G_ + (size_t)(pan_ + r_) * ld_ + kofs_,                    \
                       &lds[slot_][(j_ * 8 + wave) * 512]);                       \
        }                                                                         \
    }

    #pragma unroll
    for (int s = 0; s < 6; ++s) STAGE_HALF(s, s);
    asm volatile("s_waitcnt vmcnt(4)");
    __builtin_amdgcn_sched_barrier(0);
    __builtin_amdgcn_s_barrier();

    bf16x8 bfr[4];

#pragma unroll
    for (int i = 0; i < 4; ++i) {
#pragma unroll
        for (int p = 0; p < 8; ++p) {
            const int q = p & 3;
            const int ks = q >> 1;
            const int aslot = (p >> 2) * 4 + 2 * ks;
            const int bslot = aslot + 1;
            const int fmb = (q & 1) * 4;

            bf16x8 af[4];
#pragma unroll
            for (int f = 0; f < 4; ++f) {
                int row = wm * 128 + (fmb + f) * 16 + lr;
                af[f] = *(const bf16x8*)&lds[aslot][row * 32 + ((lg ^ (lr & 3)) << 3)];
            }
            if (q == 0 || q == 2) {
#pragma unroll
                for (int f = 0; f < 4; ++f) {
                    int row = wn * 64 + f * 16 + lr;
                    bfr[f] = *(const bf16x8*)&lds[bslot][row * 32 + ((lg ^ (lr & 3)) << 3)];
                }
            }

            {
                const int s = 8 * i + p + 6;
                if (s < 32) {
                    const int slot = (p + 6) & 7;
                    STAGE_HALF(s, slot);
                }
            }

            __builtin_amdgcn_sched_barrier(0);
            __builtin_amdgcn_s_barrier();
            asm volatile("s_waitcnt lgkmcnt(0)");
            __builtin_amdgcn_sched_barrier(0);

            __builtin_amdgcn_s_setprio(1);
#pragma unroll
            for (int f = 0; f < 4; ++f)
#pragma unroll
                for (int n = 0; n < 4; ++n)
                    acc[fmb + f][n] = __builtin_amdgcn_mfma_f32_16x16x32_bf16(
                        af[f], bfr[n], acc[fmb + f][n], 0, 0, 0);
            __builtin_amdgcn_s_setprio(0);

            if (p == 3) {
                if (i == 3) asm volatile("s_waitcnt vmcnt(0)");
                else        asm volatile("s_waitcnt vmcnt(4)");
            } else if (p == 7 && i < 3) {
                asm volatile("s_waitcnt vmcnt(4)");
            }
            __builtin_amdgcn_sched_barrier(0);
            __builtin_amdgcn_s_barrier();
        }
    }
#undef STAGE_HALF

    u16* C = Cout + (size_t)z * sCz;
#pragma unroll
    for (int fm = 0; fm < 8; ++fm)
#pragma unroll
        for (int fn = 0; fn < 4; ++fn)
#pragma unroll
            for (int reg = 0; reg < 4; ++reg) {
                int r = row0 + wm * 128 + fm * 16 + lg * 4 + reg;
                int c = col0 + wn * 64 + fn * 16 + lr;
                C[(size_t)r * N + c] = f2bf(__expf(acc[fm][fn][reg]));
            }
}

// ===========================================================================
// 256x256 8-phase PV: part[ks] = P[:, ks-half] @ vw[ks-half], inline rowsum.
// 256 blocks (1/CU), 32 K-tiles = 128 phases. Same slot/vmcnt schedule as
// gemm256_exp (verified). lda = ldb = 4096.
// ===========================================================================
__launch_bounds__(512, 2)
__global__ void pv8_kernel(const u16* __restrict__ P, const u16* __restrict__ vwT,
                           float* __restrict__ part, float* __restrict__ lpart) {
    __shared__ u16 lds[8][8192];

    const int tid = threadIdx.x;
    const int wave = tid >> 6, lane = tid & 63;
    const int lr = lane & 15, lg = lane >> 4;
    const int wm = wave >> 2, wn = wave & 3;

    // nwg=256; 16 consecutive logical blocks share one (z,ks,cx) B-chunk
    int bid = blockIdx.x;
    int lgc = (bid & 7) * 32 + (bid >> 3);
    const int rp = lgc & 15;
    const int t5 = lgc >> 4;
    const int cx = t5 & 1, ks = (t5 >> 1) & 1, z = t5 >> 2;
    const int row0 = rp * 256;   // within batch
    const int col0 = cx * 256;

    const u16* Ab = P + (size_t)z * 16777216 + (size_t)ks * 2048;
    const u16* Bb = vwT + (size_t)z * 2097152 + (size_t)ks * 2048;

    const int rb = lane >> 2;
    const int kg8 = ((lane & 3) ^ (rb & 3)) << 3;

    f32x4 acc[8][4];
#pragma unroll
    for (int i = 0; i < 8; ++i)
#pragma unroll
        for (int j = 0; j < 4; ++j) acc[i][j] = (f32x4){0.f, 0.f, 0.f, 0.f};
    float rsm[8] = {0.f, 0.f, 0.f, 0.f, 0.f, 0.f, 0.f, 0.f};

#define STAGE_HALF(s_, slot_)                                                     \
    {                                                                             \
        const int h_ = (s_)&3, ts_ = (s_) >> 2;                                   \
        const u16* G_ = (h_ & 1) ? Bb : Ab;                                       \
        const int pan_ = (h_ & 1) ? col0 : row0;                                  \
        const int kofs_ = ts_ * 64 + (h_ >> 1) * 32 + kg8;                        \
        _Pragma("unroll") for (int j_ = 0; j_ < 2; ++j_) {                        \
            int r_ = (j_ * 8 + wave) * 16 + rb;                                   \
            load_lds16(G_ + (size_t)(pan_ + r_) * 4096 + kofs_,                   \
                       &lds[slot_][(j_ * 8 + wave) * 512]);                       \
        }                                                                         \
    }

    #pragma unroll
    for (int s = 0; s < 6; ++s) STAGE_HALF(s, s);
    asm volatile("s_waitcnt vmcnt(4)");
    __builtin_amdgcn_sched_barrier(0);
    __builtin_amdgcn_s_barrier();

    bf16x8 bfr[4];

    for (int i = 0; i < 16; ++i) {
#pragma unroll
        for (int p = 0; p < 8; ++p) {
            const int q = p & 3;
            const int ksl = q >> 1;
            const int aslot = (p >> 2) * 4 + 2 * ksl;
            const int bslot = aslot + 1;
            const int fmb = (q & 1) * 4;

            bf16x8 af[4];
#pragma unroll
            for (int f = 0; f < 4; ++f) {
                int row = wm * 128 + (fmb + f) * 16 + lr;
                af[f] = *(const bf16x8*)&lds[aslot][row * 32 + ((lg ^ (lr & 3)) << 3)];
            }
            if (q == 0 || q == 2) {
#pragma unroll
                for (int f = 0; f < 4; ++f) {
                    int row = wn * 64 + f * 16 + lr;
                    bfr[f] = *(const bf16x8*)&lds[bslot][row * 32 + ((lg ^ (lr & 3)) << 3)];
                }
            }

            {
                const int s = 8 * i + p + 6;
                if (s < 128) {
                    const int slot = (p + 6) & 7;
                    STAGE_HALF(s, slot);
                }
            }

            __builtin_amdgcn_sched_barrier(0);
            __builtin_amdgcn_s_barrier();
            asm volatile("s_waitcnt lgkmcnt(0)");
            __builtin_amdgcn_sched_barrier(0);

            __builtin_amdgcn_s_setprio(1);
#pragma unroll
            for (int f = 0; f < 4; ++f)
#pragma unroll
                for (int n = 0; n < 4; ++n)
                    acc[fmb + f][n] = __builtin_amdgcn_mfma_f32_16x16x32_bf16(
                        af[f], bfr[n], acc[fmb + f][n], 0, 0, 0);
            __builtin_amdgcn_s_setprio(0);

            // inline rowsum: wn==0 waves see each (row-half, k-half) A-frag once
            if (wn == 0) {
#pragma unroll
                for (int f = 0; f < 4; ++f) {
                    union { bf16x8 v; unsigned u[4]; } cv;
                    cv.v = af[f];
#pragma unroll
                    for (int w = 0; w < 4; ++w)
                        rsm[fmb + f] += __uint_as_float(cv.u[w] << 16) +
                                        __uint_as_float(cv.u[w] & 0xffff0000u);
                }
            }

            if (p == 3) {
                if (i == 15) asm volatile("s_waitcnt vmcnt(0)");
                else         asm volatile("s_waitcnt vmcnt(4)");
            } else if (p == 7 && i < 15) {
                asm volatile("s_waitcnt vmcnt(4)");
            }
            __builtin_amdgcn_sched_barrier(0);
            __builtin_amdgcn_s_barrier();
        }
    }
#undef STAGE_HALF

    // rowsum: reduce across lg (lanes lr, lr+16, lr+32, lr+48)
    if (wn == 0) {
#pragma unroll
        for (int j = 0; j < 8; ++j) {
            rsm[j] += __shfl_xor(rsm[j], 16, 64);
            rsm[j] += __shfl_xor(rsm[j], 32, 64);
        }
        if (cx == 0 && lg == 0) {
            float* lp = lpart + (size_t)ks * 16384 + z * 4096 + row0 + wm * 128;
#pragma unroll
            for (int j = 0; j < 8; ++j) lp[j * 16 + lr] = rsm[j];
        }
    }

    float* O = part + (size_t)ks * 8388608 + ((size_t)z * 4096 + row0) * 512;
#pragma unroll
    for (int fm = 0; fm < 8; ++fm)
#pragma unroll
        for (int fn = 0; fn < 4; ++fn) {
            int c = col0 + wn * 64 + fn * 16 + lr;
#pragma unroll
            for (int reg = 0; reg < 4; ++reg) {
                int r = wm * 128 + fm * 16 + lg * 4 + reg;
                O[(size_t)r * 512 + c] = acc[fm][fn][reg];
            }
        }
}

// --------------------------- GEMM with fused fp32->bf16 A staging -----------
// 128x128 tile, BK=32, 4 waves, dbuf. A fp32 (reg-staged + cvt), B bf16 (lds).
// EPI 0: bf16 row-major store (ld = N)   EPI 1: transposed store to vwT
template <int EPI>
__launch_bounds__(256)
__global__ void gemm_f32a_kernel(const float* __restrict__ A, const u16* __restrict__ B,
                                 void* __restrict__ Cout, int N, int K, int lda, int ldb) {
    __shared__ u16 As[2][128 * 32];
    __shared__ u16 Bs[2][128 * 32];

    const int tid = threadIdx.x;
    const int wave = tid >> 6, lane = tid & 63;
    const int lr = lane & 15, lg = lane >> 4;
    const int wr = wave >> 1, wc = wave & 1;

    const int gx = gridDim.x, gy = gridDim.y;
    int bid = blockIdx.y * gx + blockIdx.x;
    const int nwg = gx * gy;
    int lgc = (bid & 7) * (nwg >> 3) + (bid >> 3);
    const int bx = lgc % gx, by = lgc / gx;
    const int row0 = by * 128, col0 = bx * 128;

    f32x4 acc[4][4];
#pragma unroll
    for (int i = 0; i < 4; ++i)
#pragma unroll
        for (int j = 0; j < 4; ++j) acc[i][j] = (f32x4){0.f, 0.f, 0.f, 0.f};

    const int KT = K >> 5;
    float4 ar[2][2];

#define LOADA(kt2)                                                                \
    {                                                                             \
        _Pragma("unroll") for (int i = 0; i < 2; ++i) {                           \
            int chunk = i * 256 + tid;                                            \
            int r = chunk >> 2, c4 = chunk & 3;                                   \
            const float* src = A + (size_t)(row0 + r) * lda + (kt2) * 32 + c4 * 8;\
            ar[i][0] = *(const float4*)src;                                       \
            ar[i][1] = *(const float4*)(src + 4);                                 \
        }                                                                         \
    }
#define WRITEA(bufi)                                                              \
    {                                                                             \
        _Pragma("unroll") for (int i = 0; i < 2; ++i) {                           \
            int chunk = i * 256 + tid;                                            \
            union { u16 u[8]; uint4 v; } cv;                                      \
            const float* f = (const float*)&ar[i][0];                             \
            _Pragma("unroll") for (int j = 0; j < 8; ++j) cv.u[j] = f2bf(f[j]);   \
            *(uint4*)&As[bufi][chunk * 8] = cv.v;                                 \
        }                                                                         \
    }
#define STAGEB(bufi, kt2)                                                         \
    {                                                                             \
        _Pragma("unroll") for (int i = 0; i < 2; ++i) {                           \
            int chunk = i * 256 + tid;                                            \
            int r = chunk >> 2, c4 = chunk & 3;                                   \
            load_lds16(B + (size_t)(col0 + r) * ldb + (kt2) * 32 + c4 * 8,        \
                       &Bs[bufi][(i * 256 + wave * 64) * 8]);                     \
        }                                                                         \
    }

    LOADA(0);
    WRITEA(0);
    LOADA(1);
    STAGEB(0, 0);
    int buf = 0;
    for (int kt = 0; kt < KT; ++kt) {
        __syncthreads();  // As[buf] writes + Bs[buf] loads visible
        if (kt + 1 < KT) {
            WRITEA(buf ^ 1);           // regs hold tile kt+1
            STAGEB(buf ^ 1, kt + 1);
        }
        if (kt + 2 < KT) LOADA(kt + 2);

        bf16x8 af[4], bfr[4];
#pragma unroll
        for (int mf = 0; mf < 4; ++mf)
            af[mf] = *(const bf16x8*)&As[buf][(wr * 64 + mf * 16 + lr) * 32 + lg * 8];
#pragma unroll
        for (int nf = 0; nf < 4; ++nf)
            bfr[nf] = *(const bf16x8*)&Bs[buf][(wc * 64 + nf * 16 + lr) * 32 + lg * 8];
#pragma unroll
        for (int mf = 0; mf < 4; ++mf)
#pragma unroll
            for (int nf = 0; nf < 4; ++nf)
                acc[mf][nf] = __builtin_amdgcn_mfma_f32_16x16x32_bf16(
                    af[mf], bfr[nf], acc[mf][nf], 0, 0, 0);
        buf ^= 1;
    }
#undef LOADA
#undef WRITEA
#undef STAGEB

    const int rbase = row0 + wr * 64;
    const int cbase = col0 + wc * 64;

    if (EPI == 0) {
        u16* C = (u16*)Cout;
#pragma unroll
        for (int mf = 0; mf < 4; ++mf)
#pragma unroll
            for (int nf = 0; nf < 4; ++nf)
#pragma unroll
                for (int reg = 0; reg < 4; ++reg) {
                    int r = rbase + mf * 16 + lg * 4 + reg;
                    int c = cbase + nf * 16 + lr;
                    C[(size_t)r * N + c] = f2bf(acc[mf][nf][reg]);
                }
    } else {  // transposed store vwT[batch][col][row%4096]
        u16* C = (u16*)Cout;
#pragma unroll
        for (int mf = 0; mf < 4; ++mf)
#pragma unroll
            for (int nf = 0; nf < 4; ++nf) {
                int rg = rbase + mf * 16 + lg * 4;
                int bsel = rg >> 12, rl = rg & 4095;
                int c = cbase + nf * 16 + lr;
                union { u16 u[4]; uint2 v; } o;
#pragma unroll
                for (int reg = 0; reg < 4; ++reg) o.u[reg] = f2bf(acc[mf][nf][reg]);
                *(uint2*)(C + ((size_t)bsel << 21) + ((size_t)c << 12) + rl) = o.v;
            }
    }
}

// --------------------------- reduce: out = (p0+p1)/l + bo -------------------
__global__ void reduce_kernel(const float* __restrict__ part,
                              const float* __restrict__ lpart,
                              const float* __restrict__ bo,
                              float* __restrict__ out) {
    int i = blockIdx.x * blockDim.x + threadIdx.x;
    int r = i >> 7, c4 = i & 127;
    float inv = 1.0f / (lpart[r] + lpart[16384 + r]);
    float4 a = ((const float4*)part)[i];
    float4 b = ((const float4*)part)[i + 2097152];
    float4 bi = ((const float4*)bo)[c4];
    float4 o;
    o.x = (a.x + b.x) * inv + bi.x;
    o.y = (a.y + b.y) * inv + bi.y;
    o.z = (a.z + b.z) * inv + bi.z;
    o.w = (a.w + b.w) * inv + bi.w;
    ((float4*)out)[i] = o;
}

// ---------------------------------------------------------------------------
extern "C" void kernel_launch(void* const* d_in, const int* in_sizes, int n_in,
                              void* d_out, int out_size, void* d_ws, size_t ws_size,
                              hipStream_t stream) {
    const float* x  = (const float*)d_in[0];
    const float* y  = (const float*)d_in[1];
    const float* Wq = (const float*)d_in[2];
    const float* Wk = (const float*)d_in[3];
    const float* Wv = (const float*)d_in[4];
    const float* Wo = (const float*)d_in[5];
    const float* bo = (const float*)d_in[6];
    float* out = (float*)d_out;

    char* ws = (char*)d_ws;
    u16*   qk   = (u16*)(ws + 0);            // 32 MB  (16384 x 1024: q|k)
    float* part = (float*)(ws + 0);          // 64 MB  [2][16384][512] (after qk dead)
    u16*   vwT  = (u16*)(ws + 67108864);     // 16 MB  [4][512][4096]
    u16*   Wqkb = (u16*)(ws + 83886080);     // 1 MB   (1024 x 512)
    u16*   Wvob = (u16*)(ws + 84934656);     // 512 KB
    float* Wvo  = (float*)(ws + 85458944);   // 1 MB
    float* lpart= (float*)(ws + 86507520);   // 128 KB [2][16384]
    u16*   P    = (u16*)(ws + 86638592);     // 128 MB [4][4096][4096]

    // 1) weights to bf16 (SCALE folded into Wq half); Wvo = Wo @ Wv
    cvt_bf16_kernel<<<128, 256, 0, stream>>>(Wq, Wqkb, 32768, SCALE_QK);
    cvt_bf16_kernel<<<128, 256, 0, stream>>>(Wk, Wqkb + 262144, 32768, 1.0f);
    wvo_kernel<<<128, 256, 0, stream>>>(Wo, Wv, Wvo);
    cvt_bf16_kernel<<<128, 256, 0, stream>>>(Wvo, Wvob, 32768, 1.0f);

    // 2) projections with fused fp32->bf16 A conversion
    gemm_f32a_kernel<0><<<dim3(8, 128), 256, 0, stream>>>(x, Wqkb, qk, 1024, 512, 512, 512);
    gemm_f32a_kernel<1><<<dim3(4, 128), 256, 0, stream>>>(y, Wvob, vwT, 512, 512, 512, 512);

    // 3) P = exp(q @ k^T) per batch — 256x256 8-phase kernel
    gemm256_exp_kernel<<<dim3(16, 16, 4), 512, 0, stream>>>(qk, qk + 512, P,
                                                            4096, 1024, 1024,
                                                            4194304, 4194304, 16777216);

    // 4) PV split-K partials + inline rowsum — 256x256 8-phase kernel
    pv8_kernel<<<256, 512, 0, stream>>>(P, vwT, part, lpart);

    // 5) out = (part0 + part1)/(l0 + l1) + bo
    reduce_kernel<<<8192, 256, 0, stream>>>(part, lpart, bo, out);
}

// Round 6
// 330.583 us; speedup vs baseline: 1.0109x; 1.0109x over previous
//
#include <hip/hip_runtime.h>
#include <hip/hip_bf16.h>

// ---------------------------------------------------------------------------
// Multihead attention (single 512-wide head), b=4, n=4096, d=inner=512, fp32 io.
//   qk = x@[Wq*s | Wk]^T   (merged projection, N=1024)
//   vw = y@(Wo@Wv)^T       (out-proj folded into V), stored transposed as vwT
//   P  = exp(q@k^T)        (no max subtraction: |S| small, fp32-safe)
//   out = (P@vw)/rowsum(P) + bo   (split-K=2 8-phase PV + deterministic reduce)
// S-GEMM and PV: 256x256 8-phase deep-pipelined kernels (T1+T2+T3+T4+T5).
// Swizzle: k-group ^= (row>>1)&3 (2-way bank spread: free per m136).
// ---------------------------------------------------------------------------

typedef unsigned short u16;
typedef __bf16 bf16x8 __attribute__((ext_vector_type(8)));
typedef float f32x4 __attribute__((ext_vector_type(4)));

#define SCALE_QK 0.044194173824159216f /* 1/sqrt(512) */

__device__ __forceinline__ u16 f2bf(float f) {
    __hip_bfloat16 h = __float2bfloat16(f);
    return __builtin_bit_cast(u16, h);
}

__device__ __forceinline__ void load_lds16(const void* g, void* l) {
    __builtin_amdgcn_global_load_lds(
        (const __attribute__((address_space(1))) void*)g,
        (__attribute__((address_space(3))) void*)l, 16, 0, 0);
}

// --------------------------- fp32 -> bf16 convert ---------------------------
__global__ void cvt_bf16_kernel(const float* __restrict__ src, u16* __restrict__ dst,
                                int n8, float scale) {
    int i = blockIdx.x * blockDim.x + threadIdx.x;
    if (i >= n8) return;
    const float4* s4 = (const float4*)src;
    float4 v0 = s4[2 * i], v1 = s4[2 * i + 1];
    union { u16 u[8]; uint4 v; } o;
    o.u[0] = f2bf(v0.x * scale); o.u[1] = f2bf(v0.y * scale);
    o.u[2] = f2bf(v0.z * scale); o.u[3] = f2bf(v0.w * scale);
    o.u[4] = f2bf(v1.x * scale); o.u[5] = f2bf(v1.y * scale);
    o.u[6] = f2bf(v1.z * scale); o.u[7] = f2bf(v1.w * scale);
    ((uint4*)dst)[i] = o.v;
}

// --------------------------- Wvo = Wo @ Wv (fp32), 4 rows/block -------------
__global__ void wvo_kernel(const float* __restrict__ Wo, const float* __restrict__ Wv,
                           float* __restrict__ Wvo) {
    int ob = blockIdx.x * 4, t = threadIdx.x;
    float a[4][2] = {{0.f, 0.f}, {0.f, 0.f}, {0.f, 0.f}, {0.f, 0.f}};
    for (int i = 0; i < 512; ++i) {
        float v0 = Wv[i * 512 + t], v1 = Wv[i * 512 + t + 256];
#pragma unroll
        for (int r = 0; r < 4; ++r) {
            float w = Wo[(ob + r) * 512 + i];
            a[r][0] += w * v0;
            a[r][1] += w * v1;
        }
    }
#pragma unroll
    for (int r = 0; r < 4; ++r) {
        Wvo[(ob + r) * 512 + t] = a[r][0];
        Wvo[(ob + r) * 512 + t + 256] = a[r][1];
    }
}

// ===========================================================================
// 256x256 8-phase S-GEMM:  P = exp(A@B^T) -> bf16.  K = 512 (8 K-tiles of 64,
// staged as 32 16KB halves). 512 threads = 8 waves (2M x 4N), wave tile 128x64.
// ===========================================================================
__launch_bounds__(512, 2)
__global__ void gemm256_exp_kernel(const u16* __restrict__ A, const u16* __restrict__ B,
                                   u16* __restrict__ Cout, int N, int lda, int ldb,
                                   long long sAz, long long sBz, long long sCz) {
    __shared__ u16 lds[8][8192];

    const int tid = threadIdx.x;
    const int wave = tid >> 6, lane = tid & 63;
    const int lr = lane & 15, lg = lane >> 4;
    const int wm = wave >> 2, wn = wave & 3;
    const int rsw = (lg ^ ((lr >> 1) & 3)) << 3;  // read-side swizzled k-group*8

    int bid = (blockIdx.z * gridDim.y + blockIdx.y) * gridDim.x + blockIdx.x;
    int lgc = (bid & 7) * 128 + (bid >> 3);
    const int bx = lgc & 15;
    int rem = lgc >> 4;
    const int by = rem & 15, z = rem >> 4;
    const int row0 = by * 256, col0 = bx * 256;

    const u16* Ab = A + (size_t)z * sAz;
    const u16* Bb = B + (size_t)z * sBz;

    const int rb = lane >> 2;
    const int kg8 = ((lane & 3) ^ ((rb >> 1) & 3)) << 3;  // stage-side swizzle

    f32x4 acc[8][4];
#pragma unroll
    for (int i = 0; i < 8; ++i)
#pragma unroll
        for (int j = 0; j < 4; ++j) acc[i][j] = (f32x4){0.f, 0.f, 0.f, 0.f};

#define STAGE_HALF(s_, slot_)                                                     \
    {                                                                             \
        const int h_ = (s_)&3, ts_ = (s_) >> 2;                                   \
        const u16* G_ = (h_ & 1) ? Bb : Ab;                                       \
        const int pan_ = (h_ & 1) ? col0 : row0;                                  \
        const int ld_ = (h_ & 1) ? ldb : lda;                                     \
        const int kofs_ = ts_ * 64 + (h_ >> 1) * 32 + kg8;                        \
        _Pragma("unroll") for (int j_ = 0; j_ < 2; ++j_) {                        \
            int r_ = (j_ * 8 + wave) * 16 + rb;                                   \
            load_lds16(G_ + (size_t)(pan_ + r_) * ld_ + kofs_,                    \
                       &lds[slot_][(j_ * 8 + wave) * 512]);                       \
        }                                                                         \
    }

    #pragma unroll
    for (int s = 0; s < 6; ++s) STAGE_HALF(s, s);
    asm volatile("s_waitcnt vmcnt(4)");
    __builtin_amdgcn_sched_barrier(0);
    __builtin_amdgcn_s_barrier();

    bf16x8 bfr[4];

#pragma unroll
    for (int i = 0; i < 4; ++i) {
#pragma unroll
        for (int p = 0; p < 8; ++p) {
            const int q = p & 3;
            const int ks = q >> 1;
            const int aslot = (p >> 2) * 4 + 2 * ks;
            const int bslot = aslot + 1;
            const int fmb = (q & 1) * 4;

            bf16x8 af[4];
#pragma unroll
            for (int f = 0; f < 4; ++f) {
                int row = wm * 128 + (fmb + f) * 16 + lr;
                af[f] = *(const bf16x8*)&lds[aslot][row * 32 + rsw];
            }
            if (q == 0 || q == 2) {
#pragma unroll
                for (int f = 0; f < 4; ++f) {
                    int row = wn * 64 + f * 16 + lr;
                    bfr[f] = *(const bf16x8*)&lds[bslot][row * 32 + rsw];
                }
            }

            {
                const int s = 8 * i + p + 6;
                if (s < 32) {
                    const int slot = (p + 6) & 7;
                    STAGE_HALF(s, slot);
                }
            }

            __builtin_amdgcn_sched_barrier(0);
            __builtin_amdgcn_s_barrier();
            asm volatile("s_waitcnt lgkmcnt(0)");
            __builtin_amdgcn_sched_barrier(0);

            __builtin_amdgcn_s_setprio(1);
#pragma unroll
            for (int f = 0; f < 4; ++f)
#pragma unroll
                for (int n = 0; n < 4; ++n)
                    acc[fmb + f][n] = __builtin_amdgcn_mfma_f32_16x16x32_bf16(
                        af[f], bfr[n], acc[fmb + f][n], 0, 0, 0);
            __builtin_amdgcn_s_setprio(0);

            if (p == 3) {
                if (i == 3) asm volatile("s_waitcnt vmcnt(0)");
                else        asm volatile("s_waitcnt vmcnt(4)");
            } else if (p == 7 && i < 3) {
                asm volatile("s_waitcnt vmcnt(4)");
            }
            __builtin_amdgcn_sched_barrier(0);
            __builtin_amdgcn_s_barrier();
        }
    }
#undef STAGE_HALF

    u16* C = Cout + (size_t)z * sCz;
#pragma unroll
    for (int fm = 0; fm < 8; ++fm)
#pragma unroll
        for (int fn = 0; fn < 4; ++fn)
#pragma unroll
            for (int reg = 0; reg < 4; ++reg) {
                int r = row0 + wm * 128 + fm * 16 + lg * 4 + reg;
                int c = col0 + wn * 64 + fn * 16 + lr;
                C[(size_t)r * N + c] = f2bf(__expf(acc[fm][fn][reg]));
            }
}

// ===========================================================================
// 256x256 8-phase PV: part[ks] = P[:, ks-half] @ vw[ks-half], inline rowsum.
// 256 blocks (1/CU), 32 K-tiles = 128 phases. lda = ldb = 4096.
// ===========================================================================
__launch_bounds__(512, 2)
__global__ void pv8_kernel(const u16* __restrict__ P, const u16* __restrict__ vwT,
                           float* __restrict__ part, float* __restrict__ lpart) {
    __shared__ u16 lds[8][8192];

    const int tid = threadIdx.x;
    const int wave = tid >> 6, lane = tid & 63;
    const int lr = lane & 15, lg = lane >> 4;
    const int wm = wave >> 2, wn = wave & 3;
    const int rsw = (lg ^ ((lr >> 1) & 3)) << 3;

    int bid = blockIdx.x;
    int lgc = (bid & 7) * 32 + (bid >> 3);
    const int rp = lgc & 15;
    const int t5 = lgc >> 4;
    const int cx = t5 & 1, ks = (t5 >> 1) & 1, z = t5 >> 2;
    const int row0 = rp * 256;
    const int col0 = cx * 256;

    const u16* Ab = P + (size_t)z * 16777216 + (size_t)ks * 2048;
    const u16* Bb = vwT + (size_t)z * 2097152 + (size_t)ks * 2048;

    const int rb = lane >> 2;
    const int kg8 = ((lane & 3) ^ ((rb >> 1) & 3)) << 3;

    f32x4 acc[8][4];
#pragma unroll
    for (int i = 0; i < 8; ++i)
#pragma unroll
        for (int j = 0; j < 4; ++j) acc[i][j] = (f32x4){0.f, 0.f, 0.f, 0.f};
    float rsm[8] = {0.f, 0.f, 0.f, 0.f, 0.f, 0.f, 0.f, 0.f};

#define STAGE_HALF(s_, slot_)                                                     \
    {                                                                             \
        const int h_ = (s_)&3, ts_ = (s_) >> 2;                                   \
        const u16* G_ = (h_ & 1) ? Bb : Ab;                                       \
        const int pan_ = (h_ & 1) ? col0 : row0;                                  \
        const int kofs_ = ts_ * 64 + (h_ >> 1) * 32 + kg8;                        \
        _Pragma("unroll") for (int j_ = 0; j_ < 2; ++j_) {                        \
            int r_ = (j_ * 8 + wave) * 16 + rb;                                   \
            load_lds16(G_ + (size_t)(pan_ + r_) * 4096 + kofs_,                   \
                       &lds[slot_][(j_ * 8 + wave) * 512]);                       \
        }                                                                         \
    }

    #pragma unroll
    for (int s = 0; s < 6; ++s) STAGE_HALF(s, s);
    asm volatile("s_waitcnt vmcnt(4)");
    __builtin_amdgcn_sched_barrier(0);
    __builtin_amdgcn_s_barrier();

    bf16x8 bfr[4];

    for (int i = 0; i < 16; ++i) {
#pragma unroll
        for (int p = 0; p < 8; ++p) {
            const int q = p & 3;
            const int ksl = q >> 1;
            const int aslot = (p >> 2) * 4 + 2 * ksl;
            const int bslot = aslot + 1;
            const int fmb = (q & 1) * 4;

            bf16x8 af[4];
#pragma unroll
            for (int f = 0; f < 4; ++f) {
                int row = wm * 128 + (fmb + f) * 16 + lr;
                af[f] = *(const bf16x8*)&lds[aslot][row * 32 + rsw];
            }
            if (q == 0 || q == 2) {
#pragma unroll
                for (int f = 0; f < 4; ++f) {
                    int row = wn * 64 + f * 16 + lr;
                    bfr[f] = *(const bf16x8*)&lds[bslot][row * 32 + rsw];
                }
            }

            {
                const int s = 8 * i + p + 6;
                if (s < 128) {
                    const int slot = (p + 6) & 7;
                    STAGE_HALF(s, slot);
                }
            }

            __builtin_amdgcn_sched_barrier(0);
            __builtin_amdgcn_s_barrier();
            asm volatile("s_waitcnt lgkmcnt(0)");
            __builtin_amdgcn_sched_barrier(0);

            __builtin_amdgcn_s_setprio(1);
#pragma unroll
            for (int f = 0; f < 4; ++f)
#pragma unroll
                for (int n = 0; n < 4; ++n)
                    acc[fmb + f][n] = __builtin_amdgcn_mfma_f32_16x16x32_bf16(
                        af[f], bfr[n], acc[fmb + f][n], 0, 0, 0);
            __builtin_amdgcn_s_setprio(0);

            // inline rowsum: wn==0 waves see each (row-half, k-half) A-frag once
            if (wn == 0) {
#pragma unroll
                for (int f = 0; f < 4; ++f) {
                    union { bf16x8 v; unsigned u[4]; } cv;
                    cv.v = af[f];
#pragma unroll
                    for (int w = 0; w < 4; ++w)
                        rsm[fmb + f] += __uint_as_float(cv.u[w] << 16) +
                                        __uint_as_float(cv.u[w] & 0xffff0000u);
                }
            }

            if (p == 3) {
                if (i == 15) asm volatile("s_waitcnt vmcnt(0)");
                else         asm volatile("s_waitcnt vmcnt(4)");
            } else if (p == 7 && i < 15) {
                asm volatile("s_waitcnt vmcnt(4)");
            }
            __builtin_amdgcn_sched_barrier(0);
            __builtin_amdgcn_s_barrier();
        }
    }
#undef STAGE_HALF

    // rowsum: reduce across lg (lanes lr, lr+16, lr+32, lr+48)
    if (wn == 0) {
#pragma unroll
        for (int j = 0; j < 8; ++j) {
            rsm[j] += __shfl_xor(rsm[j], 16, 64);
            rsm[j] += __shfl_xor(rsm[j], 32, 64);
        }
        if (cx == 0 && lg == 0) {
            float* lp = lpart + (size_t)ks * 16384 + z * 4096 + row0 + wm * 128;
#pragma unroll
            for (int j = 0; j < 8; ++j) lp[j * 16 + lr] = rsm[j];
        }
    }

    float* O = part + (size_t)ks * 8388608 + ((size_t)z * 4096 + row0) * 512;
#pragma unroll
    for (int fm = 0; fm < 8; ++fm)
#pragma unroll
        for (int fn = 0; fn < 4; ++fn) {
            int c = col0 + wn * 64 + fn * 16 + lr;
#pragma unroll
            for (int reg = 0; reg < 4; ++reg) {
                int r = wm * 128 + fm * 16 + lg * 4 + reg;
                O[(size_t)r * 512 + c] = acc[fm][fn][reg];
            }
        }
}

// --------------------------- GEMM: C = A @ B^T (m97 128x128) ----------------
// EPI 0: bf16 row-major store (ld = N)      (merged qk projection)
// EPI 1: bf16 TRANSPOSED store to vwT[batch][col][row&4095]
template <int EPI>
__launch_bounds__(256)
__global__ void gemm_bt_kernel(const u16* __restrict__ A, const u16* __restrict__ B,
                               void* __restrict__ Cout, int N, int K, int lda, int ldb,
                               long long sAz, long long sBz, long long sCz) {
    __shared__ u16 As[2][128 * 32];
    __shared__ u16 Bs[2][128 * 32];

    const int tid = threadIdx.x;
    const int wave = tid >> 6, lane = tid & 63;
    const int lr = lane & 15, lg = lane >> 4;
    const int wr = wave >> 1, wc = wave & 1;

    const int gx = gridDim.x, gy = gridDim.y;
    int bid = (blockIdx.z * gy + blockIdx.y) * gx + blockIdx.x;
    const int nwg = gx * gy * gridDim.z;
    int lgc = (bid & 7) * (nwg >> 3) + (bid >> 3);
    const int bx = lgc % gx;
    int rem = lgc / gx;
    const int by = rem % gy, z = rem / gy;
    const int row0 = by * 128, col0 = bx * 128;

    const u16* Ab = A + (size_t)z * sAz;
    const u16* Bb = B + (size_t)z * sBz;

    f32x4 acc[4][4];
#pragma unroll
    for (int i = 0; i < 4; ++i)
#pragma unroll
        for (int j = 0; j < 4; ++j) acc[i][j] = (f32x4){0.f, 0.f, 0.f, 0.f};

    const int KT = K >> 5;

#define STAGE(bufi, kt2)                                                          \
    {                                                                             \
        _Pragma("unroll") for (int i = 0; i < 2; ++i) {                           \
            int chunk = i * 256 + tid;                                            \
            int r = chunk >> 2, c4 = chunk & 3;                                   \
            load_lds16(Ab + (size_t)(row0 + r) * lda + (kt2) * 32 + c4 * 8,       \
                       &As[bufi][(i * 256 + wave * 64) * 8]);                     \
            load_lds16(Bb + (size_t)(col0 + r) * ldb + (kt2) * 32 + c4 * 8,       \
                       &Bs[bufi][(i * 256 + wave * 64) * 8]);                     \
        }                                                                         \
    }

    STAGE(0, 0);
    int buf = 0;
    for (int kt = 0; kt < KT; ++kt) {
        __syncthreads();
        if (kt + 1 < KT) STAGE(buf ^ 1, kt + 1);

        bf16x8 af[4], bfr[4];
#pragma unroll
        for (int mf = 0; mf < 4; ++mf)
            af[mf] = *(const bf16x8*)&As[buf][(wr * 64 + mf * 16 + lr) * 32 + lg * 8];
#pragma unroll
        for (int nf = 0; nf < 4; ++nf)
            bfr[nf] = *(const bf16x8*)&Bs[buf][(wc * 64 + nf * 16 + lr) * 32 + lg * 8];
#pragma unroll
        for (int mf = 0; mf < 4; ++mf)
#pragma unroll
            for (int nf = 0; nf < 4; ++nf)
                acc[mf][nf] = __builtin_amdgcn_mfma_f32_16x16x32_bf16(
                    af[mf], bfr[nf], acc[mf][nf], 0, 0, 0);
        buf ^= 1;
    }
#undef STAGE

    const int rbase = row0 + wr * 64;
    const int cbase = col0 + wc * 64;

    if (EPI == 0) {
        u16* C = (u16*)Cout + (size_t)z * sCz;
#pragma unroll
        for (int mf = 0; mf < 4; ++mf)
#pragma unroll
            for (int nf = 0; nf < 4; ++nf)
#pragma unroll
                for (int reg = 0; reg < 4; ++reg) {
                    int r = rbase + mf * 16 + lg * 4 + reg;
                    int c = cbase + nf * 16 + lr;
                    C[(size_t)r * N + c] = f2bf(acc[mf][nf][reg]);
                }
    } else {  // EPI == 1: transposed store vwT[batch][col][row%4096]
        u16* C = (u16*)Cout;
#pragma unroll
        for (int mf = 0; mf < 4; ++mf)
#pragma unroll
            for (int nf = 0; nf < 4; ++nf) {
                int rg = rbase + mf * 16 + lg * 4;
                int bsel = rg >> 12, rl = rg & 4095;
                int c = cbase + nf * 16 + lr;
                union { u16 u[4]; uint2 v; } o;
#pragma unroll
                for (int reg = 0; reg < 4; ++reg) o.u[reg] = f2bf(acc[mf][nf][reg]);
                *(uint2*)(C + ((size_t)bsel << 21) + ((size_t)c << 12) + rl) = o.v;
            }
    }
}

// --------------------------- reduce: out = (p0+p1)/l + bo -------------------
__global__ void reduce_kernel(const float* __restrict__ part,
                              const float* __restrict__ lpart,
                              const float* __restrict__ bo,
                              float* __restrict__ out) {
    int i = blockIdx.x * blockDim.x + threadIdx.x;
    int r = i >> 7, c4 = i & 127;
    float inv = 1.0f / (lpart[r] + lpart[16384 + r]);
    float4 a = ((const float4*)part)[i];
    float4 b = ((const float4*)part)[i + 2097152];
    float4 bi = ((const float4*)bo)[c4];
    float4 o;
    o.x = (a.x + b.x) * inv + bi.x;
    o.y = (a.y + b.y) * inv + bi.y;
    o.z = (a.z + b.z) * inv + bi.z;
    o.w = (a.w + b.w) * inv + bi.w;
    ((float4*)out)[i] = o;
}

// ---------------------------------------------------------------------------
extern "C" void kernel_launch(void* const* d_in, const int* in_sizes, int n_in,
                              void* d_out, int out_size, void* d_ws, size_t ws_size,
                              hipStream_t stream) {
    const float* x  = (const float*)d_in[0];
    const float* y  = (const float*)d_in[1];
    const float* Wq = (const float*)d_in[2];
    const float* Wk = (const float*)d_in[3];
    const float* Wv = (const float*)d_in[4];
    const float* Wo = (const float*)d_in[5];
    const float* bo = (const float*)d_in[6];
    float* out = (float*)d_out;

    char* ws = (char*)d_ws;
    u16*   xb   = (u16*)(ws + 0);            // 16 MB  (16384 x 512)
    u16*   yb   = (u16*)(ws + 16777216);     // 16 MB
    u16*   qk   = (u16*)(ws + 33554432);     // 32 MB  (16384 x 1024: q|k)
    float* part = (float*)(ws + 0);          // 64 MB  [2][16384][512] (reuses xb/yb/qk)
    u16*   vwT  = (u16*)(ws + 67108864);     // 16 MB  [4][512][4096]
    u16*   Wqkb = (u16*)(ws + 83886080);     // 1 MB   (1024 x 512)
    u16*   Wvob = (u16*)(ws + 84934656);     // 512 KB
    float* Wvo  = (float*)(ws + 85458944);   // 1 MB
    float* lpart= (float*)(ws + 86507520);   // 128 KB [2][16384]
    u16*   P    = (u16*)(ws + 86638592);     // 128 MB [4][4096][4096]

    // 1) convert inputs to bf16 (SCALE folded into Wq half of Wqkb)
    cvt_bf16_kernel<<<4096, 256, 0, stream>>>(x, xb, 1048576, 1.0f);
    cvt_bf16_kernel<<<4096, 256, 0, stream>>>(y, yb, 1048576, 1.0f);
    cvt_bf16_kernel<<<128, 256, 0, stream>>>(Wq, Wqkb, 32768, SCALE_QK);
    cvt_bf16_kernel<<<128, 256, 0, stream>>>(Wk, Wqkb + 262144, 32768, 1.0f);

    // 2) Wvo = Wo @ Wv (fp32) -> bf16
    wvo_kernel<<<128, 256, 0, stream>>>(Wo, Wv, Wvo);
    cvt_bf16_kernel<<<128, 256, 0, stream>>>(Wvo, Wvob, 32768, 1.0f);

    // 3) merged projection: qk = xb @ Wqkb^T ; vwT = (yb @ Wvob^T)^T
    gemm_bt_kernel<0><<<dim3(8, 128, 1), 256, 0, stream>>>(xb, Wqkb, qk,
                                                           1024, 512, 512, 512, 0, 0, 0);
    gemm_bt_kernel<1><<<dim3(4, 128, 1), 256, 0, stream>>>(yb, Wvob, vwT,
                                                           512, 512, 512, 512, 0, 0, 0);

    // 4) P = exp(q @ k^T) per batch — 256x256 8-phase kernel (fixed swizzle)
    gemm256_exp_kernel<<<dim3(16, 16, 4), 512, 0, stream>>>(qk, qk + 512, P,
                                                            4096, 1024, 1024,
                                                            4194304, 4194304, 16777216);

    // 5) PV split-K partials + inline rowsum — 8-phase kernel (fixed swizzle)
    pv8_kernel<<<256, 512, 0, stream>>>(P, vwT, part, lpart);

    // 6) out = (part0 + part1)/(l0 + l1) + bo
    reduce_kernel<<<8192, 256, 0, stream>>>(part, lpart, bo, out);
}

// Round 7
// 330.316 us; speedup vs baseline: 1.0117x; 1.0008x over previous
//
#include <hip/hip_runtime.h>
#include <hip/hip_bf16.h>

// ---------------------------------------------------------------------------
// Multihead attention (single 512-wide head), b=4, n=4096, d=inner=512, fp32 io.
//   qk = x@[Wq*s | Wk]^T   (merged projection, N=1024)
//   vw = y@(Wo@Wv)^T       (out-proj folded into V), stored transposed as vwT
//   P  = exp(q@k^T)        (no max subtraction: |S| small, fp32-safe)
//   out = (P@vw)/rowsum(P) + bo   (split-K=2 8-phase PV + deterministic reduce)
// S-GEMM and PV: 256x256 8-phase deep-pipelined kernels (T1+T2+T3+T4+T5).
// Swizzle: k-group ^= (row>>1)&3 (verified: bank conflicts = 0).
// R7: removed manual lgkmcnt(0) drain before MFMA — let SIWaitcnt insert
//     fine-grained lgkmcnt so LDS read drain overlaps MFMA issue (m141/m97).
// ---------------------------------------------------------------------------

typedef unsigned short u16;
typedef __bf16 bf16x8 __attribute__((ext_vector_type(8)));
typedef float f32x4 __attribute__((ext_vector_type(4)));

#define SCALE_QK 0.044194173824159216f /* 1/sqrt(512) */

__device__ __forceinline__ u16 f2bf(float f) {
    __hip_bfloat16 h = __float2bfloat16(f);
    return __builtin_bit_cast(u16, h);
}

__device__ __forceinline__ void load_lds16(const void* g, void* l) {
    __builtin_amdgcn_global_load_lds(
        (const __attribute__((address_space(1))) void*)g,
        (__attribute__((address_space(3))) void*)l, 16, 0, 0);
}

// --------------------------- fp32 -> bf16 convert ---------------------------
__global__ void cvt_bf16_kernel(const float* __restrict__ src, u16* __restrict__ dst,
                                int n8, float scale) {
    int i = blockIdx.x * blockDim.x + threadIdx.x;
    if (i >= n8) return;
    const float4* s4 = (const float4*)src;
    float4 v0 = s4[2 * i], v1 = s4[2 * i + 1];
    union { u16 u[8]; uint4 v; } o;
    o.u[0] = f2bf(v0.x * scale); o.u[1] = f2bf(v0.y * scale);
    o.u[2] = f2bf(v0.z * scale); o.u[3] = f2bf(v0.w * scale);
    o.u[4] = f2bf(v1.x * scale); o.u[5] = f2bf(v1.y * scale);
    o.u[6] = f2bf(v1.z * scale); o.u[7] = f2bf(v1.w * scale);
    ((uint4*)dst)[i] = o.v;
}

// --------------------------- Wvo = Wo @ Wv (fp32), 4 rows/block -------------
__global__ void wvo_kernel(const float* __restrict__ Wo, const float* __restrict__ Wv,
                           float* __restrict__ Wvo) {
    int ob = blockIdx.x * 4, t = threadIdx.x;
    float a[4][2] = {{0.f, 0.f}, {0.f, 0.f}, {0.f, 0.f}, {0.f, 0.f}};
    for (int i = 0; i < 512; ++i) {
        float v0 = Wv[i * 512 + t], v1 = Wv[i * 512 + t + 256];
#pragma unroll
        for (int r = 0; r < 4; ++r) {
            float w = Wo[(ob + r) * 512 + i];
            a[r][0] += w * v0;
            a[r][1] += w * v1;
        }
    }
#pragma unroll
    for (int r = 0; r < 4; ++r) {
        Wvo[(ob + r) * 512 + t] = a[r][0];
        Wvo[(ob + r) * 512 + t + 256] = a[r][1];
    }
}

// ===========================================================================
// 256x256 8-phase S-GEMM:  P = exp(A@B^T) -> bf16.  K = 512 (8 K-tiles of 64,
// staged as 32 16KB halves). 512 threads = 8 waves (2M x 4N), wave tile 128x64.
// ===========================================================================
__launch_bounds__(512, 2)
__global__ void gemm256_exp_kernel(const u16* __restrict__ A, const u16* __restrict__ B,
                                   u16* __restrict__ Cout, int N, int lda, int ldb,
                                   long long sAz, long long sBz, long long sCz) {
    __shared__ u16 lds[8][8192];

    const int tid = threadIdx.x;
    const int wave = tid >> 6, lane = tid & 63;
    const int lr = lane & 15, lg = lane >> 4;
    const int wm = wave >> 2, wn = wave & 3;
    const int rsw = (lg ^ ((lr >> 1) & 3)) << 3;  // read-side swizzled k-group*8

    int bid = (blockIdx.z * gridDim.y + blockIdx.y) * gridDim.x + blockIdx.x;
    int lgc = (bid & 7) * 128 + (bid >> 3);
    const int bx = lgc & 15;
    int rem = lgc >> 4;
    const int by = rem & 15, z = rem >> 4;
    const int row0 = by * 256, col0 = bx * 256;

    const u16* Ab = A + (size_t)z * sAz;
    const u16* Bb = B + (size_t)z * sBz;

    const int rb = lane >> 2;
    const int kg8 = ((lane & 3) ^ ((rb >> 1) & 3)) << 3;  // stage-side swizzle

    f32x4 acc[8][4];
#pragma unroll
    for (int i = 0; i < 8; ++i)
#pragma unroll
        for (int j = 0; j < 4; ++j) acc[i][j] = (f32x4){0.f, 0.f, 0.f, 0.f};

#define STAGE_HALF(s_, slot_)                                                     \
    {                                                                             \
        const int h_ = (s_)&3, ts_ = (s_) >> 2;                                   \
        const u16* G_ = (h_ & 1) ? Bb : Ab;                                       \
        const int pan_ = (h_ & 1) ? col0 : row0;                                  \
        const int ld_ = (h_ & 1) ? ldb : lda;                                     \
        const int kofs_ = ts_ * 64 + (h_ >> 1) * 32 + kg8;                        \
        _Pragma("unroll") for (int j_ = 0; j_ < 2; ++j_) {                        \
            int r_ = (j_ * 8 + wave) * 16 + rb;                                   \
            load_lds16(G_ + (size_t)(pan_ + r_) * ld_ + kofs_,                    \
                       &lds[slot_][(j_ * 8 + wave) * 512]);                       \
        }                                                                         \
    }

    #pragma unroll
    for (int s = 0; s < 6; ++s) STAGE_HALF(s, s);
    asm volatile("s_waitcnt vmcnt(4)");
    __builtin_amdgcn_sched_barrier(0);
    __builtin_amdgcn_s_barrier();

    bf16x8 bfr[4];

#pragma unroll
    for (int i = 0; i < 4; ++i) {
#pragma unroll
        for (int p = 0; p < 8; ++p) {
            const int q = p & 3;
            const int ks = q >> 1;
            const int aslot = (p >> 2) * 4 + 2 * ks;
            const int bslot = aslot + 1;
            const int fmb = (q & 1) * 4;

            bf16x8 af[4];
#pragma unroll
            for (int f = 0; f < 4; ++f) {
                int row = wm * 128 + (fmb + f) * 16 + lr;
                af[f] = *(const bf16x8*)&lds[aslot][row * 32 + rsw];
            }
            if (q == 0 || q == 2) {
#pragma unroll
                for (int f = 0; f < 4; ++f) {
                    int row = wn * 64 + f * 16 + lr;
                    bfr[f] = *(const bf16x8*)&lds[bslot][row * 32 + rsw];
                }
            }

            {
                const int s = 8 * i + p + 6;
                if (s < 32) {
                    const int slot = (p + 6) & 7;
                    STAGE_HALF(s, slot);
                }
            }

            __builtin_amdgcn_sched_barrier(0);
            __builtin_amdgcn_s_barrier();
            // NOTE: no manual lgkmcnt(0) here — SIWaitcnt inserts fine-grained
            // per-use lgkmcnt so the LDS drain overlaps the MFMA issue.

            __builtin_amdgcn_s_setprio(1);
#pragma unroll
            for (int f = 0; f < 4; ++f)
#pragma unroll
                for (int n = 0; n < 4; ++n)
                    acc[fmb + f][n] = __builtin_amdgcn_mfma_f32_16x16x32_bf16(
                        af[f], bfr[n], acc[fmb + f][n], 0, 0, 0);
            __builtin_amdgcn_s_setprio(0);

            if (p == 3) {
                if (i == 3) asm volatile("s_waitcnt vmcnt(0)");
                else        asm volatile("s_waitcnt vmcnt(4)");
            } else if (p == 7 && i < 3) {
                asm volatile("s_waitcnt vmcnt(4)");
            }
            __builtin_amdgcn_sched_barrier(0);
            __builtin_amdgcn_s_barrier();
        }
    }
#undef STAGE_HALF

    u16* C = Cout + (size_t)z * sCz;
#pragma unroll
    for (int fm = 0; fm < 8; ++fm)
#pragma unroll
        for (int fn = 0; fn < 4; ++fn)
#pragma unroll
            for (int reg = 0; reg < 4; ++reg) {
                int r = row0 + wm * 128 + fm * 16 + lg * 4 + reg;
                int c = col0 + wn * 64 + fn * 16 + lr;
                C[(size_t)r * N + c] = f2bf(__expf(acc[fm][fn][reg]));
            }
}

// ===========================================================================
// 256x256 8-phase PV: part[ks] = P[:, ks-half] @ vw[ks-half], inline rowsum.
// 256 blocks (1/CU), 32 K-tiles = 128 phases. lda = ldb = 4096.
// ===========================================================================
__launch_bounds__(512, 2)
__global__ void pv8_kernel(const u16* __restrict__ P, const u16* __restrict__ vwT,
                           float* __restrict__ part, float* __restrict__ lpart) {
    __shared__ u16 lds[8][8192];

    const int tid = threadIdx.x;
    const int wave = tid >> 6, lane = tid & 63;
    const int lr = lane & 15, lg = lane >> 4;
    const int wm = wave >> 2, wn = wave & 3;
    const int rsw = (lg ^ ((lr >> 1) & 3)) << 3;

    int bid = blockIdx.x;
    int lgc = (bid & 7) * 32 + (bid >> 3);
    const int rp = lgc & 15;
    const int t5 = lgc >> 4;
    const int cx = t5 & 1, ks = (t5 >> 1) & 1, z = t5 >> 2;
    const int row0 = rp * 256;
    const int col0 = cx * 256;

    const u16* Ab = P + (size_t)z * 16777216 + (size_t)ks * 2048;
    const u16* Bb = vwT + (size_t)z * 2097152 + (size_t)ks * 2048;

    const int rb = lane >> 2;
    const int kg8 = ((lane & 3) ^ ((rb >> 1) & 3)) << 3;

    f32x4 acc[8][4];
#pragma unroll
    for (int i = 0; i < 8; ++i)
#pragma unroll
        for (int j = 0; j < 4; ++j) acc[i][j] = (f32x4){0.f, 0.f, 0.f, 0.f};
    float rsm[8] = {0.f, 0.f, 0.f, 0.f, 0.f, 0.f, 0.f, 0.f};

#define STAGE_HALF(s_, slot_)                                                     \
    {                                                                             \
        const int h_ = (s_)&3, ts_ = (s_) >> 2;                                   \
        const u16* G_ = (h_ & 1) ? Bb : Ab;                                       \
        const int pan_ = (h_ & 1) ? col0 : row0;                                  \
        const int kofs_ = ts_ * 64 + (h_ >> 1) * 32 + kg8;                        \
        _Pragma("unroll") for (int j_ = 0; j_ < 2; ++j_) {                        \
            int r_ = (j_ * 8 + wave) * 16 + rb;                                   \
            load_lds16(G_ + (size_t)(pan_ + r_) * 4096 + kofs_,                   \
                       &lds[slot_][(j_ * 8 + wave) * 512]);                       \
        }                                                                         \
    }

    #pragma unroll
    for (int s = 0; s < 6; ++s) STAGE_HALF(s, s);
    asm volatile("s_waitcnt vmcnt(4)");
    __builtin_amdgcn_sched_barrier(0);
    __builtin_amdgcn_s_barrier();

    bf16x8 bfr[4];

    for (int i = 0; i < 16; ++i) {
#pragma unroll
        for (int p = 0; p < 8; ++p) {
            const int q = p & 3;
            const int ksl = q >> 1;
            const int aslot = (p >> 2) * 4 + 2 * ksl;
            const int bslot = aslot + 1;
            const int fmb = (q & 1) * 4;

            bf16x8 af[4];
#pragma unroll
            for (int f = 0; f < 4; ++f) {
                int row = wm * 128 + (fmb + f) * 16 + lr;
                af[f] = *(const bf16x8*)&lds[aslot][row * 32 + rsw];
            }
            if (q == 0 || q == 2) {
#pragma unroll
                for (int f = 0; f < 4; ++f) {
                    int row = wn * 64 + f * 16 + lr;
                    bfr[f] = *(const bf16x8*)&lds[bslot][row * 32 + rsw];
                }
            }

            {
                const int s = 8 * i + p + 6;
                if (s < 128) {
                    const int slot = (p + 6) & 7;
                    STAGE_HALF(s, slot);
                }
            }

            __builtin_amdgcn_sched_barrier(0);
            __builtin_amdgcn_s_barrier();
            // no manual lgkmcnt(0): compiler inserts fine-grained waits

            __builtin_amdgcn_s_setprio(1);
#pragma unroll
            for (int f = 0; f < 4; ++f)
#pragma unroll
                for (int n = 0; n < 4; ++n)
                    acc[fmb + f][n] = __builtin_amdgcn_mfma_f32_16x16x32_bf16(
                        af[f], bfr[n], acc[fmb + f][n], 0, 0, 0);
            __builtin_amdgcn_s_setprio(0);

            // inline rowsum: wn==0 waves see each (row-half, k-half) A-frag once
            if (wn == 0) {
#pragma unroll
                for (int f = 0; f < 4; ++f) {
                    union { bf16x8 v; unsigned u[4]; } cv;
                    cv.v = af[f];
#pragma unroll
                    for (int w = 0; w < 4; ++w)
                        rsm[fmb + f] += __uint_as_float(cv.u[w] << 16) +
                                        __uint_as_float(cv.u[w] & 0xffff0000u);
                }
            }

            if (p == 3) {
                if (i == 15) asm volatile("s_waitcnt vmcnt(0)");
                else         asm volatile("s_waitcnt vmcnt(4)");
            } else if (p == 7 && i < 15) {
                asm volatile("s_waitcnt vmcnt(4)");
            }
            __builtin_amdgcn_sched_barrier(0);
            __builtin_amdgcn_s_barrier();
        }
    }
#undef STAGE_HALF

    // rowsum: reduce across lg (lanes lr, lr+16, lr+32, lr+48)
    if (wn == 0) {
#pragma unroll
        for (int j = 0; j < 8; ++j) {
            rsm[j] += __shfl_xor(rsm[j], 16, 64);
            rsm[j] += __shfl_xor(rsm[j], 32, 64);
        }
        if (cx == 0 && lg == 0) {
            float* lp = lpart + (size_t)ks * 16384 + z * 4096 + row0 + wm * 128;
#pragma unroll
            for (int j = 0; j < 8; ++j) lp[j * 16 + lr] = rsm[j];
        }
    }

    float* O = part + (size_t)ks * 8388608 + ((size_t)z * 4096 + row0) * 512;
#pragma unroll
    for (int fm = 0; fm < 8; ++fm)
#pragma unroll
        for (int fn = 0; fn < 4; ++fn) {
            int c = col0 + wn * 64 + fn * 16 + lr;
#pragma unroll
            for (int reg = 0; reg < 4; ++reg) {
                int r = wm * 128 + fm * 16 + lg * 4 + reg;
                O[(size_t)r * 512 + c] = acc[fm][fn][reg];
            }
        }
}

// --------------------------- GEMM: C = A @ B^T (m97 128x128) ----------------
// EPI 0: bf16 row-major store (ld = N)      (merged qk projection)
// EPI 1: bf16 TRANSPOSED store to vwT[batch][col][row&4095]
template <int EPI>
__launch_bounds__(256)
__global__ void gemm_bt_kernel(const u16* __restrict__ A, const u16* __restrict__ B,
                               void* __restrict__ Cout, int N, int K, int lda, int ldb,
                               long long sAz, long long sBz, long long sCz) {
    __shared__ u16 As[2][128 * 32];
    __shared__ u16 Bs[2][128 * 32];

    const int tid = threadIdx.x;
    const int wave = tid >> 6, lane = tid & 63;
    const int lr = lane & 15, lg = lane >> 4;
    const int wr = wave >> 1, wc = wave & 1;

    const int gx = gridDim.x, gy = gridDim.y;
    int bid = (blockIdx.z * gy + blockIdx.y) * gx + blockIdx.x;
    const int nwg = gx * gy * gridDim.z;
    int lgc = (bid & 7) * (nwg >> 3) + (bid >> 3);
    const int bx = lgc % gx;
    int rem = lgc / gx;
    const int by = rem % gy, z = rem / gy;
    const int row0 = by * 128, col0 = bx * 128;

    const u16* Ab = A + (size_t)z * sAz;
    const u16* Bb = B + (size_t)z * sBz;

    f32x4 acc[4][4];
#pragma unroll
    for (int i = 0; i < 4; ++i)
#pragma unroll
        for (int j = 0; j < 4; ++j) acc[i][j] = (f32x4){0.f, 0.f, 0.f, 0.f};

    const int KT = K >> 5;

#define STAGE(bufi, kt2)                                                          \
    {                                                                             \
        _Pragma("unroll") for (int i = 0; i < 2; ++i) {                           \
            int chunk = i * 256 + tid;                                            \
            int r = chunk >> 2, c4 = chunk & 3;                                   \
            load_lds16(Ab + (size_t)(row0 + r) * lda + (kt2) * 32 + c4 * 8,       \
                       &As[bufi][(i * 256 + wave * 64) * 8]);                     \
            load_lds16(Bb + (size_t)(col0 + r) * ldb + (kt2) * 32 + c4 * 8,       \
                       &Bs[bufi][(i * 256 + wave * 64) * 8]);                     \
        }                                                                         \
    }

    STAGE(0, 0);
    int buf = 0;
    for (int kt = 0; kt < KT; ++kt) {
        __syncthreads();
        if (kt + 1 < KT) STAGE(buf ^ 1, kt + 1);

        bf16x8 af[4], bfr[4];
#pragma unroll
        for (int mf = 0; mf < 4; ++mf)
            af[mf] = *(const bf16x8*)&As[buf][(wr * 64 + mf * 16 + lr) * 32 + lg * 8];
#pragma unroll
        for (int nf = 0; nf < 4; ++nf)
            bfr[nf] = *(const bf16x8*)&Bs[buf][(wc * 64 + nf * 16 + lr) * 32 + lg * 8];
#pragma unroll
        for (int mf = 0; mf < 4; ++mf)
#pragma unroll
            for (int nf = 0; nf < 4; ++nf)
                acc[mf][nf] = __builtin_amdgcn_mfma_f32_16x16x32_bf16(
                    af[mf], bfr[nf], acc[mf][nf], 0, 0, 0);
        buf ^= 1;
    }
#undef STAGE

    const int rbase = row0 + wr * 64;
    const int cbase = col0 + wc * 64;

    if (EPI == 0) {
        u16* C = (u16*)Cout + (size_t)z * sCz;
#pragma unroll
        for (int mf = 0; mf < 4; ++mf)
#pragma unroll
            for (int nf = 0; nf < 4; ++nf)
#pragma unroll
                for (int reg = 0; reg < 4; ++reg) {
                    int r = rbase + mf * 16 + lg * 4 + reg;
                    int c = cbase + nf * 16 + lr;
                    C[(size_t)r * N + c] = f2bf(acc[mf][nf][reg]);
                }
    } else {  // EPI == 1: transposed store vwT[batch][col][row%4096]
        u16* C = (u16*)Cout;
#pragma unroll
        for (int mf = 0; mf < 4; ++mf)
#pragma unroll
            for (int nf = 0; nf < 4; ++nf) {
                int rg = rbase + mf * 16 + lg * 4;
                int bsel = rg >> 12, rl = rg & 4095;
                int c = cbase + nf * 16 + lr;
                union { u16 u[4]; uint2 v; } o;
#pragma unroll
                for (int reg = 0; reg < 4; ++reg) o.u[reg] = f2bf(acc[mf][nf][reg]);
                *(uint2*)(C + ((size_t)bsel << 21) + ((size_t)c << 12) + rl) = o.v;
            }
    }
}

// --------------------------- reduce: out = (p0+p1)/l + bo -------------------
__global__ void reduce_kernel(const float* __restrict__ part,
                              const float* __restrict__ lpart,
                              const float* __restrict__ bo,
                              float* __restrict__ out) {
    int i = blockIdx.x * blockDim.x + threadIdx.x;
    int r = i >> 7, c4 = i & 127;
    float inv = 1.0f / (lpart[r] + lpart[16384 + r]);
    float4 a = ((const float4*)part)[i];
    float4 b = ((const float4*)part)[i + 2097152];
    float4 bi = ((const float4*)bo)[c4];
    float4 o;
    o.x = (a.x + b.x) * inv + bi.x;
    o.y = (a.y + b.y) * inv + bi.y;
    o.z = (a.z + b.z) * inv + bi.z;
    o.w = (a.w + b.w) * inv + bi.w;
    ((float4*)out)[i] = o;
}

// ---------------------------------------------------------------------------
extern "C" void kernel_launch(void* const* d_in, const int* in_sizes, int n_in,
                              void* d_out, int out_size, void* d_ws, size_t ws_size,
                              hipStream_t stream) {
    const float* x  = (const float*)d_in[0];
    const float* y  = (const float*)d_in[1];
    const float* Wq = (const float*)d_in[2];
    const float* Wk = (const float*)d_in[3];
    const float* Wv = (const float*)d_in[4];
    const float* Wo = (const float*)d_in[5];
    const float* bo = (const float*)d_in[6];
    float* out = (float*)d_out;

    char* ws = (char*)d_ws;
    u16*   xb   = (u16*)(ws + 0);            // 16 MB  (16384 x 512)
    u16*   yb   = (u16*)(ws + 16777216);     // 16 MB
    u16*   qk   = (u16*)(ws + 33554432);     // 32 MB  (16384 x 1024: q|k)
    float* part = (float*)(ws + 0);          // 64 MB  [2][16384][512] (reuses xb/yb/qk)
    u16*   vwT  = (u16*)(ws + 67108864);     // 16 MB  [4][512][4096]
    u16*   Wqkb = (u16*)(ws + 83886080);     // 1 MB   (1024 x 512)
    u16*   Wvob = (u16*)(ws + 84934656);     // 512 KB
    float* Wvo  = (float*)(ws + 85458944);   // 1 MB
    float* lpart= (float*)(ws + 86507520);   // 128 KB [2][16384]
    u16*   P    = (u16*)(ws + 86638592);     // 128 MB [4][4096][4096]

    // 1) convert inputs to bf16 (SCALE folded into Wq half of Wqkb)
    cvt_bf16_kernel<<<4096, 256, 0, stream>>>(x, xb, 1048576, 1.0f);
    cvt_bf16_kernel<<<4096, 256, 0, stream>>>(y, yb, 1048576, 1.0f);
    cvt_bf16_kernel<<<128, 256, 0, stream>>>(Wq, Wqkb, 32768, SCALE_QK);
    cvt_bf16_kernel<<<128, 256, 0, stream>>>(Wk, Wqkb + 262144, 32768, 1.0f);

    // 2) Wvo = Wo @ Wv (fp32) -> bf16
    wvo_kernel<<<128, 256, 0, stream>>>(Wo, Wv, Wvo);
    cvt_bf16_kernel<<<128, 256, 0, stream>>>(Wvo, Wvob, 32768, 1.0f);

    // 3) merged projection: qk = xb @ Wqkb^T ; vwT = (yb @ Wvob^T)^T
    gemm_bt_kernel<0><<<dim3(8, 128, 1), 256, 0, stream>>>(xb, Wqkb, qk,
                                                           1024, 512, 512, 512, 0, 0, 0);
    gemm_bt_kernel<1><<<dim3(4, 128, 1), 256, 0, stream>>>(yb, Wvob, vwT,
                                                           512, 512, 512, 512, 0, 0, 0);

    // 4) P = exp(q @ k^T) per batch — 256x256 8-phase kernel
    gemm256_exp_kernel<<<dim3(16, 16, 4), 512, 0, stream>>>(qk, qk + 512, P,
                                                            4096, 1024, 1024,
                                                            4194304, 4194304, 16777216);

    // 5) PV split-K partials + inline rowsum — 8-phase kernel
    pv8_kernel<<<256, 512, 0, stream>>>(P, vwT, part, lpart);

    // 6) out = (part0 + part1)/(l0 + l1) + bo
    reduce_kernel<<<8192, 256, 0, stream>>>(part, lpart, bo, out);
}

// Round 9
// 322.849 us; speedup vs baseline: 1.0351x; 1.0231x over previous
//
#include <hip/hip_runtime.h>
#include <hip/hip_bf16.h>

// ---------------------------------------------------------------------------
// Multihead attention (single 512-wide head), b=4, n=4096, d=inner=512, fp32 io.
//   qk = x@[Wq*s | Wk]^T   (merged projection, N=1024)
//   vw = y@(Wo@Wv)^T       (out-proj folded into V), stored transposed as vwT
//   P  = exp(q@k^T)        (no max subtraction: |S| small, fp32-safe)
//   out = (P@vw)/rowsum(P) + bo   (split-K=2 8-phase PV + deterministic reduce)
// S-GEMM and PV: 256x256 8-phase deep-pipelined kernels (T1+T2+T3+T4+T5).
// Swizzle: k-group ^= (row>>1)&3 (verified: bank conflicts = 0).
// R8: removed ALL sched_barrier(0) order-pins from the steady loops (m141:
//     order-pinning defeats the scheduler; m201's proven template has none).
// ---------------------------------------------------------------------------

typedef unsigned short u16;
typedef __bf16 bf16x8 __attribute__((ext_vector_type(8)));
typedef float f32x4 __attribute__((ext_vector_type(4)));

#define SCALE_QK 0.044194173824159216f /* 1/sqrt(512) */

__device__ __forceinline__ u16 f2bf(float f) {
    __hip_bfloat16 h = __float2bfloat16(f);
    return __builtin_bit_cast(u16, h);
}

__device__ __forceinline__ void load_lds16(const void* g, void* l) {
    __builtin_amdgcn_global_load_lds(
        (const __attribute__((address_space(1))) void*)g,
        (__attribute__((address_space(3))) void*)l, 16, 0, 0);
}

// ------------------- fp32 -> bf16 convert, two sources, one launch ----------
__global__ void cvt2_bf16_kernel(const float* __restrict__ s0, const float* __restrict__ s1,
                                 u16* __restrict__ dst, int n8, float scale0, float scale1) {
    int i = blockIdx.x * blockDim.x + threadIdx.x;
    const float4* s4;
    float scale;
    int j;
    if (i < n8) { s4 = (const float4*)s0; scale = scale0; j = i; }
    else        { s4 = (const float4*)s1; scale = scale1; j = i - n8; }
    float4 v0 = s4[2 * j], v1 = s4[2 * j + 1];
    union { u16 u[8]; uint4 v; } o;
    o.u[0] = f2bf(v0.x * scale); o.u[1] = f2bf(v0.y * scale);
    o.u[2] = f2bf(v0.z * scale); o.u[3] = f2bf(v0.w * scale);
    o.u[4] = f2bf(v1.x * scale); o.u[5] = f2bf(v1.y * scale);
    o.u[6] = f2bf(v1.z * scale); o.u[7] = f2bf(v1.w * scale);
    ((uint4*)dst)[i] = o.v;
}

// ----------------- Wvo = Wo @ Wv (fp32 acc) -> bf16 direct, 4 rows/block ----
__global__ void wvo_kernel(const float* __restrict__ Wo, const float* __restrict__ Wv,
                           u16* __restrict__ Wvob) {
    int ob = blockIdx.x * 4, t = threadIdx.x;
    float a[4][2] = {{0.f, 0.f}, {0.f, 0.f}, {0.f, 0.f}, {0.f, 0.f}};
    for (int i = 0; i < 512; ++i) {
        float v0 = Wv[i * 512 + t], v1 = Wv[i * 512 + t + 256];
#pragma unroll
        for (int r = 0; r < 4; ++r) {
            float w = Wo[(ob + r) * 512 + i];
            a[r][0] += w * v0;
            a[r][1] += w * v1;
        }
    }
#pragma unroll
    for (int r = 0; r < 4; ++r) {
        Wvob[(ob + r) * 512 + t] = f2bf(a[r][0]);
        Wvob[(ob + r) * 512 + t + 256] = f2bf(a[r][1]);
    }
}

// ===========================================================================
// 256x256 8-phase S-GEMM:  P = exp(A@B^T) -> bf16.  K = 512 (8 K-tiles of 64,
// staged as 32 16KB halves). 512 threads = 8 waves (2M x 4N), wave tile 128x64.
// ===========================================================================
__launch_bounds__(512, 2)
__global__ void gemm256_exp_kernel(const u16* __restrict__ A, const u16* __restrict__ B,
                                   u16* __restrict__ Cout, int N, int lda, int ldb,
                                   long long sAz, long long sBz, long long sCz) {
    __shared__ u16 lds[8][8192];

    const int tid = threadIdx.x;
    const int wave = tid >> 6, lane = tid & 63;
    const int lr = lane & 15, lg = lane >> 4;
    const int wm = wave >> 2, wn = wave & 3;
    const int rsw = (lg ^ ((lr >> 1) & 3)) << 3;  // read-side swizzled k-group*8

    int bid = (blockIdx.z * gridDim.y + blockIdx.y) * gridDim.x + blockIdx.x;
    int lgc = (bid & 7) * 128 + (bid >> 3);
    const int bx = lgc & 15;
    int rem = lgc >> 4;
    const int by = rem & 15, z = rem >> 4;
    const int row0 = by * 256, col0 = bx * 256;

    const u16* Ab = A + (size_t)z * sAz;
    const u16* Bb = B + (size_t)z * sBz;

    const int rb = lane >> 2;
    const int kg8 = ((lane & 3) ^ ((rb >> 1) & 3)) << 3;  // stage-side swizzle

    f32x4 acc[8][4];
#pragma unroll
    for (int i = 0; i < 8; ++i)
#pragma unroll
        for (int j = 0; j < 4; ++j) acc[i][j] = (f32x4){0.f, 0.f, 0.f, 0.f};

#define STAGE_HALF(s_, slot_)                                                     \
    {                                                                             \
        const int h_ = (s_)&3, ts_ = (s_) >> 2;                                   \
        const u16* G_ = (h_ & 1) ? Bb : Ab;                                       \
        const int pan_ = (h_ & 1) ? col0 : row0;                                  \
        const int ld_ = (h_ & 1) ? ldb : lda;                                     \
        const int kofs_ = ts_ * 64 + (h_ >> 1) * 32 + kg8;                        \
        _Pragma("unroll") for (int j_ = 0; j_ < 2; ++j_) {                        \
            int r_ = (j_ * 8 + wave) * 16 + rb;                                   \
            load_lds16(G_ + (size_t)(pan_ + r_) * ld_ + kofs_,                    \
                       &lds[slot_][(j_ * 8 + wave) * 512]);                       \
        }                                                                         \
    }

    #pragma unroll
    for (int s = 0; s < 6; ++s) STAGE_HALF(s, s);
    asm volatile("s_waitcnt vmcnt(4)");
    __builtin_amdgcn_s_barrier();

    bf16x8 bfr[4];

#pragma unroll
    for (int i = 0; i < 4; ++i) {
#pragma unroll
        for (int p = 0; p < 8; ++p) {
            const int q = p & 3;
            const int ks = q >> 1;
            const int aslot = (p >> 2) * 4 + 2 * ks;
            const int bslot = aslot + 1;
            const int fmb = (q & 1) * 4;

            bf16x8 af[4];
#pragma unroll
            for (int f = 0; f < 4; ++f) {
                int row = wm * 128 + (fmb + f) * 16 + lr;
                af[f] = *(const bf16x8*)&lds[aslot][row * 32 + rsw];
            }
            if (q == 0 || q == 2) {
#pragma unroll
                for (int f = 0; f < 4; ++f) {
                    int row = wn * 64 + f * 16 + lr;
                    bfr[f] = *(const bf16x8*)&lds[bslot][row * 32 + rsw];
                }
            }

            {
                const int s = 8 * i + p + 6;
                if (s < 32) {
                    const int slot = (p + 6) & 7;
                    STAGE_HALF(s, slot);
                }
            }

            __builtin_amdgcn_s_barrier();

            __builtin_amdgcn_s_setprio(1);
#pragma unroll
            for (int f = 0; f < 4; ++f)
#pragma unroll
                for (int n = 0; n < 4; ++n)
                    acc[fmb + f][n] = __builtin_amdgcn_mfma_f32_16x16x32_bf16(
                        af[f], bfr[n], acc[fmb + f][n], 0, 0, 0);
            __builtin_amdgcn_s_setprio(0);

            if (p == 3) {
                if (i == 3) asm volatile("s_waitcnt vmcnt(0)");
                else        asm volatile("s_waitcnt vmcnt(4)");
            } else if (p == 7 && i < 3) {
                asm volatile("s_waitcnt vmcnt(4)");
            }
            __builtin_amdgcn_s_barrier();
        }
    }
#undef STAGE_HALF

    u16* C = Cout + (size_t)z * sCz;
#pragma unroll
    for (int fm = 0; fm < 8; ++fm)
#pragma unroll
        for (int fn = 0; fn < 4; ++fn)
#pragma unroll
            for (int reg = 0; reg < 4; ++reg) {
                int r = row0 + wm * 128 + fm * 16 + lg * 4 + reg;
                int c = col0 + wn * 64 + fn * 16 + lr;
                C[(size_t)r * N + c] = f2bf(__expf(acc[fm][fn][reg]));
            }
}

// ===========================================================================
// 256x256 8-phase PV: part[ks] = P[:, ks-half] @ vw[ks-half], inline rowsum.
// 256 blocks (1/CU), 32 K-tiles = 128 phases. lda = ldb = 4096.
// ===========================================================================
__launch_bounds__(512, 2)
__global__ void pv8_kernel(const u16* __restrict__ P, const u16* __restrict__ vwT,
                           float* __restrict__ part, float* __restrict__ lpart) {
    __shared__ u16 lds[8][8192];

    const int tid = threadIdx.x;
    const int wave = tid >> 6, lane = tid & 63;
    const int lr = lane & 15, lg = lane >> 4;
    const int wm = wave >> 2, wn = wave & 3;
    const int rsw = (lg ^ ((lr >> 1) & 3)) << 3;

    int bid = blockIdx.x;
    int lgc = (bid & 7) * 32 + (bid >> 3);
    const int rp = lgc & 15;
    const int t5 = lgc >> 4;
    const int cx = t5 & 1, ks = (t5 >> 1) & 1, z = t5 >> 2;
    const int row0 = rp * 256;
    const int col0 = cx * 256;

    const u16* Ab = P + (size_t)z * 16777216 + (size_t)ks * 2048;
    const u16* Bb = vwT + (size_t)z * 2097152 + (size_t)ks * 2048;

    const int rb = lane >> 2;
    const int kg8 = ((lane & 3) ^ ((rb >> 1) & 3)) << 3;

    f32x4 acc[8][4];
#pragma unroll
    for (int i = 0; i < 8; ++i)
#pragma unroll
        for (int j = 0; j < 4; ++j) acc[i][j] = (f32x4){0.f, 0.f, 0.f, 0.f};
    float rsm[8] = {0.f, 0.f, 0.f, 0.f, 0.f, 0.f, 0.f, 0.f};

#define STAGE_HALF(s_, slot_)                                                     \
    {                                                                             \
        const int h_ = (s_)&3, ts_ = (s_) >> 2;                                   \
        const u16* G_ = (h_ & 1) ? Bb : Ab;                                       \
        const int pan_ = (h_ & 1) ? col0 : row0;                                  \
        const int kofs_ = ts_ * 64 + (h_ >> 1) * 32 + kg8;                        \
        _Pragma("unroll") for (int j_ = 0; j_ < 2; ++j_) {                        \
            int r_ = (j_ * 8 + wave) * 16 + rb;                                   \
            load_lds16(G_ + (size_t)(pan_ + r_) * 4096 + kofs_,                   \
                       &lds[slot_][(j_ * 8 + wave) * 512]);                       \
        }                                                                         \
    }

    #pragma unroll
    for (int s = 0; s < 6; ++s) STAGE_HALF(s, s);
    asm volatile("s_waitcnt vmcnt(4)");
    __builtin_amdgcn_s_barrier();

    bf16x8 bfr[4];

    for (int i = 0; i < 16; ++i) {
#pragma unroll
        for (int p = 0; p < 8; ++p) {
            const int q = p & 3;
            const int ksl = q >> 1;
            const int aslot = (p >> 2) * 4 + 2 * ksl;
            const int bslot = aslot + 1;
            const int fmb = (q & 1) * 4;

            bf16x8 af[4];
#pragma unroll
            for (int f = 0; f < 4; ++f) {
                int row = wm * 128 + (fmb + f) * 16 + lr;
                af[f] = *(const bf16x8*)&lds[aslot][row * 32 + rsw];
            }
            if (q == 0 || q == 2) {
#pragma unroll
                for (int f = 0; f < 4; ++f) {
                    int row = wn * 64 + f * 16 + lr;
                    bfr[f] = *(const bf16x8*)&lds[bslot][row * 32 + rsw];
                }
            }

            {
                const int s = 8 * i + p + 6;
                if (s < 128) {
                    const int slot = (p + 6) & 7;
                    STAGE_HALF(s, slot);
                }
            }

            __builtin_amdgcn_s_barrier();

            __builtin_amdgcn_s_setprio(1);
#pragma unroll
            for (int f = 0; f < 4; ++f)
#pragma unroll
                for (int n = 0; n < 4; ++n)
                    acc[fmb + f][n] = __builtin_amdgcn_mfma_f32_16x16x32_bf16(
                        af[f], bfr[n], acc[fmb + f][n], 0, 0, 0);
            __builtin_amdgcn_s_setprio(0);

            // inline rowsum: wn==0 waves see each (row-half, k-half) A-frag once
            if (wn == 0) {
#pragma unroll
                for (int f = 0; f < 4; ++f) {
                    union { bf16x8 v; unsigned u[4]; } cv;
                    cv.v = af[f];
#pragma unroll
                    for (int w = 0; w < 4; ++w)
                        rsm[fmb + f] += __uint_as_float(cv.u[w] << 16) +
                                        __uint_as_float(cv.u[w] & 0xffff0000u);
                }
            }

            if (p == 3) {
                if (i == 15) asm volatile("s_waitcnt vmcnt(0)");
                else         asm volatile("s_waitcnt vmcnt(4)");
            } else if (p == 7 && i < 15) {
                asm volatile("s_waitcnt vmcnt(4)");
            }
            __builtin_amdgcn_s_barrier();
        }
    }
#undef STAGE_HALF

    // rowsum: reduce across lg (lanes lr, lr+16, lr+32, lr+48)
    if (wn == 0) {
#pragma unroll
        for (int j = 0; j < 8; ++j) {
            rsm[j] += __shfl_xor(rsm[j], 16, 64);
            rsm[j] += __shfl_xor(rsm[j], 32, 64);
        }
        if (cx == 0 && lg == 0) {
            float* lp = lpart + (size_t)ks * 16384 + z * 4096 + row0 + wm * 128;
#pragma unroll
            for (int j = 0; j < 8; ++j) lp[j * 16 + lr] = rsm[j];
        }
    }

    float* O = part + (size_t)ks * 8388608 + ((size_t)z * 4096 + row0) * 512;
#pragma unroll
    for (int fm = 0; fm < 8; ++fm)
#pragma unroll
        for (int fn = 0; fn < 4; ++fn) {
            int c = col0 + wn * 64 + fn * 16 + lr;
#pragma unroll
            for (int reg = 0; reg < 4; ++reg) {
                int r = wm * 128 + fm * 16 + lg * 4 + reg;
                O[(size_t)r * 512 + c] = acc[fm][fn][reg];
            }
        }
}

// --------------------------- GEMM: C = A @ B^T (m97 128x128) ----------------
// EPI 0: bf16 row-major store (ld = N)      (merged qk projection)
// EPI 1: bf16 TRANSPOSED store to vwT[batch][col][row&4095]
template <int EPI>
__launch_bounds__(256)
__global__ void gemm_bt_kernel(const u16* __restrict__ A, const u16* __restrict__ B,
                               void* __restrict__ Cout, int N, int K, int lda, int ldb,
                               long long sAz, long long sBz, long long sCz) {
    __shared__ u16 As[2][128 * 32];
    __shared__ u16 Bs[2][128 * 32];

    const int tid = threadIdx.x;
    const int wave = tid >> 6, lane = tid & 63;
    const int lr = lane & 15, lg = lane >> 4;
    const int wr = wave >> 1, wc = wave & 1;

    const int gx = gridDim.x, gy = gridDim.y;
    int bid = (blockIdx.z * gy + blockIdx.y) * gx + blockIdx.x;
    const int nwg = gx * gy * gridDim.z;
    int lgc = (bid & 7) * (nwg >> 3) + (bid >> 3);
    const int bx = lgc % gx;
    int rem = lgc / gx;
    const int by = rem % gy, z = rem / gy;
    const int row0 = by * 128, col0 = bx * 128;

    const u16* Ab = A + (size_t)z * sAz;
    const u16* Bb = B + (size_t)z * sBz;

    f32x4 acc[4][4];
#pragma unroll
    for (int i = 0; i < 4; ++i)
#pragma unroll
        for (int j = 0; j < 4; ++j) acc[i][j] = (f32x4){0.f, 0.f, 0.f, 0.f};

    const int KT = K >> 5;

#define STAGE(bufi, kt2)                                                          \
    {                                                                             \
        _Pragma("unroll") for (int i = 0; i < 2; ++i) {                           \
            int chunk = i * 256 + tid;                                            \
            int r = chunk >> 2, c4 = chunk & 3;                                   \
            load_lds16(Ab + (size_t)(row0 + r) * lda + (kt2) * 32 + c4 * 8,       \
                       &As[bufi][(i * 256 + wave * 64) * 8]);                     \
            load_lds16(Bb + (size_t)(col0 + r) * ldb + (kt2) * 32 + c4 * 8,       \
                       &Bs[bufi][(i * 256 + wave * 64) * 8]);                     \
        }                                                                         \
    }

    STAGE(0, 0);
    int buf = 0;
    for (int kt = 0; kt < KT; ++kt) {
        __syncthreads();
        if (kt + 1 < KT) STAGE(buf ^ 1, kt + 1);

        bf16x8 af[4], bfr[4];
#pragma unroll
        for (int mf = 0; mf < 4; ++mf)
            af[mf] = *(const bf16x8*)&As[buf][(wr * 64 + mf * 16 + lr) * 32 + lg * 8];
#pragma unroll
        for (int nf = 0; nf < 4; ++nf)
            bfr[nf] = *(const bf16x8*)&Bs[buf][(wc * 64 + nf * 16 + lr) * 32 + lg * 8];
#pragma unroll
        for (int mf = 0; mf < 4; ++mf)
#pragma unroll
            for (int nf = 0; nf < 4; ++nf)
                acc[mf][nf] = __builtin_amdgcn_mfma_f32_16x16x32_bf16(
                    af[mf], bfr[nf], acc[mf][nf], 0, 0, 0);
        buf ^= 1;
    }
#undef STAGE

    const int rbase = row0 + wr * 64;
    const int cbase = col0 + wc * 64;

    if (EPI == 0) {
        u16* C = (u16*)Cout + (size_t)z * sCz;
#pragma unroll
        for (int mf = 0; mf < 4; ++mf)
#pragma unroll
            for (int nf = 0; nf < 4; ++nf)
#pragma unroll
                for (int reg = 0; reg < 4; ++reg) {
                    int r = rbase + mf * 16 + lg * 4 + reg;
                    int c = cbase + nf * 16 + lr;
                    C[(size_t)r * N + c] = f2bf(acc[mf][nf][reg]);
                }
    } else {  // EPI == 1: transposed store vwT[batch][col][row%4096]
        u16* C = (u16*)Cout;
#pragma unroll
        for (int mf = 0; mf < 4; ++mf)
#pragma unroll
            for (int nf = 0; nf < 4; ++nf) {
                int rg = rbase + mf * 16 + lg * 4;
                int bsel = rg >> 12, rl = rg & 4095;
                int c = cbase + nf * 16 + lr;
                union { u16 u[4]; uint2 v; } o;
#pragma unroll
                for (int reg = 0; reg < 4; ++reg) o.u[reg] = f2bf(acc[mf][nf][reg]);
                *(uint2*)(C + ((size_t)bsel << 21) + ((size_t)c << 12) + rl) = o.v;
            }
    }
}

// --------------------------- reduce: out = (p0+p1)/l + bo -------------------
__global__ void reduce_kernel(const float* __restrict__ part,
                              const float* __restrict__ lpart,
                              const float* __restrict__ bo,
                              float* __restrict__ out) {
    int i = blockIdx.x * blockDim.x + threadIdx.x;
    int r = i >> 7, c4 = i & 127;
    float inv = 1.0f / (lpart[r] + lpart[16384 + r]);
    float4 a = ((const float4*)part)[i];
    float4 b = ((const float4*)part)[i + 2097152];
    float4 bi = ((const float4*)bo)[c4];
    float4 o;
    o.x = (a.x + b.x) * inv + bi.x;
    o.y = (a.y + b.y) * inv + bi.y;
    o.z = (a.z + b.z) * inv + bi.z;
    o.w = (a.w + b.w) * inv + bi.w;
    ((float4*)out)[i] = o;
}

// ---------------------------------------------------------------------------
extern "C" void kernel_launch(void* const* d_in, const int* in_sizes, int n_in,
                              void* d_out, int out_size, void* d_ws, size_t ws_size,
                              hipStream_t stream) {
    const float* x  = (const float*)d_in[0];
    const float* y  = (const float*)d_in[1];
    const float* Wq = (const float*)d_in[2];
    const float* Wk = (const float*)d_in[3];
    const float* Wv = (const float*)d_in[4];
    const float* Wo = (const float*)d_in[5];
    const float* bo = (const float*)d_in[6];
    float* out = (float*)d_out;

    char* ws = (char*)d_ws;
    u16*   xb   = (u16*)(ws + 0);            // 16 MB  (16384 x 512); yb follows contiguously
    u16*   qk   = (u16*)(ws + 33554432);     // 32 MB  (16384 x 1024: q|k)
    float* part = (float*)(ws + 0);          // 64 MB  [2][16384][512] (reuses xb/yb/qk)
    u16*   vwT  = (u16*)(ws + 67108864);     // 16 MB  [4][512][4096]
    u16*   Wqkb = (u16*)(ws + 83886080);     // 1 MB   (1024 x 512)
    u16*   Wvob = (u16*)(ws + 84934656);     // 512 KB
    float* lpart= (float*)(ws + 86507520);   // 128 KB [2][16384]
    u16*   P    = (u16*)(ws + 86638592);     // 128 MB [4][4096][4096]

    // 1) inputs + weights to bf16 (SCALE folded into Wq half); Wvo -> bf16 direct
    cvt2_bf16_kernel<<<8192, 256, 0, stream>>>(x, y, xb, 1048576, 1.0f, 1.0f);
    cvt2_bf16_kernel<<<256, 256, 0, stream>>>(Wq, Wk, Wqkb, 32768, SCALE_QK, 1.0f);
    wvo_kernel<<<128, 256, 0, stream>>>(Wo, Wv, Wvob);

    // 2) merged projection: qk = xb @ Wqkb^T ; vwT = (yb @ Wvob^T)^T
    gemm_bt_kernel<0><<<dim3(8, 128, 1), 256, 0, stream>>>(xb, Wqkb, qk,
                                                           1024, 512, 512, 512, 0, 0, 0);
    gemm_bt_kernel<1><<<dim3(4, 128, 1), 256, 0, stream>>>(xb + 8388608, Wvob, vwT,
                                                           512, 512, 512, 512, 0, 0, 0);

    // 3) P = exp(q @ k^T) per batch — 256x256 8-phase kernel
    gemm256_exp_kernel<<<dim3(16, 16, 4), 512, 0, stream>>>(qk, qk + 512, P,
                                                            4096, 1024, 1024,
                                                            4194304, 4194304, 16777216);

    // 4) PV split-K partials + inline rowsum — 8-phase kernel
    pv8_kernel<<<256, 512, 0, stream>>>(P, vwT, part, lpart);

    // 5) out = (part0 + part1)/(l0 + l1) + bo
    reduce_kernel<<<8192, 256, 0, stream>>>(part, lpart, bo, out);
}